// Round 8
// baseline (20730.467 us; speedup 1.0000x reference)
//
#include <hip/hip_runtime.h>
#include <stdint.h>

#define B_  256
#define S_  512
#define D_  64
#define H_  256
#define G3_ 768

typedef __attribute__((ext_vector_type(8))) short s8v;   // 8 bf16 (4 VGPRs)
typedef __attribute__((ext_vector_type(4))) short s4v;   // 4 bf16 (2 VGPRs)
typedef __attribute__((ext_vector_type(4))) float f4v;   // MFMA accumulator
typedef __attribute__((ext_vector_type(4))) float f4r;   // raw float4 (NT-capable)

#define MF(a, b, c) __builtin_amdgcn_mfma_f32_16x16x32_bf16((a), (b), (c), 0, 0, 0)

__device__ __forceinline__ unsigned short f2bf(float x) {  // RNE
  unsigned u = __float_as_uint(x);
  unsigned r = (u + 0x7fffu + ((u >> 16) & 1u)) >> 16;
  return (unsigned short)r;
}
__device__ __forceinline__ float bf2f(unsigned short s) {
  return __uint_as_float(((unsigned)s) << 16);
}
__device__ __forceinline__ float sigm(float x) {
  return __builtin_amdgcn_rcpf(1.f + __expf(-x));
}
__device__ __forceinline__ float tanh_f(float x) {
  return 1.f - 2.f * __builtin_amdgcn_rcpf(1.f + __expf(2.f * x));
}

// ---------------------------------------------------------------------------
// MFMA bf16-split input GEMM (unchanged).
// ---------------------------------------------------------------------------
__global__ __launch_bounds__(256) void gemm_mfma(
    const float* __restrict__ A, const float* __restrict__ W,
    const float* __restrict__ bias, float* __restrict__ C,
    int K, int chsh, int t0)
{
  const int g0 = blockIdx.x * 64;
  const int r0 = blockIdx.y * 64;
  const int tid = threadIdx.x;
  const int w = tid >> 6, l = tid & 63;
  const int fr = l & 15, fq = l >> 4;

  __shared__ unsigned short Ah[64][40], Al[64][40];
  __shared__ unsigned short Wh[64][40], Wl[64][40];

  f4v acc[4] = {};

  const int row = tid >> 2, q = tid & 3;
  const int CHm1 = (1 << chsh) - 1;
  const int r = r0 + row;
  const int rg = ((r >> chsh) * S_) + t0 + (r & CHm1);
  const float* ap = A + (size_t)rg * K + q * 8;
  const float* wp = W + (size_t)(g0 + row) * K + q * 8;

  for (int k0 = 0; k0 < K; k0 += 32) {
    float4 a0 = *(const float4*)(ap + k0);
    float4 a1 = *(const float4*)(ap + k0 + 4);
    float4 w0 = *(const float4*)(wp + k0);
    float4 w1 = *(const float4*)(wp + k0 + 4);
    __syncthreads();
    float av[8] = {a0.x,a0.y,a0.z,a0.w,a1.x,a1.y,a1.z,a1.w};
    float wv[8] = {w0.x,w0.y,w0.z,w0.w,w1.x,w1.y,w1.z,w1.w};
    unsigned short ah[8], al_[8], wh[8], wl_[8];
    #pragma unroll
    for (int i = 0; i < 8; ++i) {
      ah[i]  = f2bf(av[i]);  al_[i] = f2bf(av[i] - bf2f(ah[i]));
      wh[i]  = f2bf(wv[i]);  wl_[i] = f2bf(wv[i] - bf2f(wh[i]));
    }
    *(s8v*)&Ah[row][q*8] = *(s8v*)ah;  *(s8v*)&Al[row][q*8] = *(s8v*)al_;
    *(s8v*)&Wh[row][q*8] = *(s8v*)wh;  *(s8v*)&Wl[row][q*8] = *(s8v*)wl_;
    __syncthreads();

    s8v a_hi = *(const s8v*)&Ah[w*16 + fr][fq*8];
    s8v a_lo = *(const s8v*)&Al[w*16 + fr][fq*8];
    #pragma unroll
    for (int c = 0; c < 4; ++c) {
      s8v b_hi = *(const s8v*)&Wh[c*16 + fr][fq*8];
      s8v b_lo = *(const s8v*)&Wl[c*16 + fr][fq*8];
      acc[c] = MF(a_hi, b_hi, acc[c]);
      acc[c] = MF(a_lo, b_hi, acc[c]);
      acc[c] = MF(a_hi, b_lo, acc[c]);
    }
  }

  const int orow = r0 + w * 16 + fq * 4;
  #pragma unroll
  for (int c = 0; c < 4; ++c) {
    const float bi = bias[g0 + c * 16 + fr];
    #pragma unroll
    for (int i = 0; i < 4; ++i) {
      float v = acc[c][i] + bi;
      __builtin_nontemporal_store(v, &C[(size_t)(orow + i) * G3_ + g0 + c * 16 + fr]);
    }
  }
}

// ---------------------------------------------------------------------------
// Pack W_hh into MFMA fragment order, split hi/lo bf16 (unchanged).
// ---------------------------------------------------------------------------
__global__ __launch_bounds__(64) void pack_whh(
    const float* __restrict__ Whh, unsigned short* __restrict__ Whp,
    unsigned short* __restrict__ Wlp)
{
  const int gti = blockIdx.x, kc = blockIdx.y, lane = threadIdx.x;
  const int row = gti * 16 + (lane & 15);
  const int k0  = kc * 32 + (lane >> 4) * 8;
  const float* src = &Whh[(size_t)row * H_ + k0];
  unsigned short hi8[8], lo8[8];
  #pragma unroll
  for (int s = 0; s < 8; ++s) {
    float f = src[s];
    unsigned short hi = f2bf(f);
    hi8[s] = hi;
    lo8[s] = f2bf(f - bf2f(hi));
  }
  const size_t o = ((size_t)(gti * 8 + kc) * 64 + lane) * 8;
  *(s8v*)&Whp[o] = *(s8v*)hi8;
  *(s8v*)&Wlp[o] = *(s8v*)lo8;
}

__global__ __launch_bounds__(768) void bias2_k(
    const float* __restrict__ bih, const float* __restrict__ bhh,
    float* __restrict__ bias2)
{
  int g = threadIdx.x;
  bias2[g] = bih[g] + (g < 512 ? bhh[g] : 0.f);
}

// ---------------------------------------------------------------------------
// MFMA GRU scan v3: 16 WGs x 1024 threads (16 waves -> 4 waves/SIMD, 128-VGPR
// fit). Wave w owns units [16w,16w+16): one 16-row tile per gate
// (gti r=w, z=16+w, n=32+w). r-hi resident in VGPR (32), n-hi resident in
// LDS (128KB), {z-hi, r-lo, z-lo, n-lo} streamed from L2 double-buffered.
// h state lives in the ystage LDS buffer (doubles as y-flush stage): each
// step, every thread reads its own h-quad (hp4), each wave builds a half
// k-chunk of the shared A-fragments from ystage (no shfl chain), 9 MFMA/kc.
// Exactly 2 barriers/step, zero cross-WG sync.
// ---------------------------------------------------------------------------
__global__ __launch_bounds__(1024, 4) void gru_scan(
    const float* __restrict__ gx, const unsigned short* __restrict__ Whp,
    const unsigned short* __restrict__ Wlp, const float* __restrict__ bhh,
    float* __restrict__ hbuf, float* __restrict__ y,
    int CH, int t0c, int last)
{
  const int bid = blockIdx.x;          // 16
  const int b0  = bid * 16;
  const int tid = threadIdx.x;
  const int wid = tid >> 6, lane = tid & 63;
  const int bb = lane & 15;            // batch-local (D col)
  const int fq = lane >> 4;            // row quad (D rows 4fq..4fq+3)

  extern __shared__ unsigned short lds_[];
  unsigned short* WhN = lds_;                       // [16 w][8 kc][512] = 128KB
  unsigned short* Ahh = lds_ + 65536;               // [8 kc][512] = 8KB
  unsigned short* Ahl = Ahh + 4096;                 // 8KB
  float* ystage = (float*)(Ahl + 4096);             // [16 bb][256 u] = 16KB, swz

  const s8v* WhpV = (const s8v*)Whp;
  const s8v* WlpV = (const s8v*)Wlp;

  // resident r-hi tile (32 VGPR)
  s8v whr[8];
  #pragma unroll
  for (int kc = 0; kc < 8; ++kc)
    whr[kc] = WhpV[(wid * 8 + kc) * 64 + lane];
  // n-hi tile -> LDS (each wave its own 8KB region)
  #pragma unroll
  for (int kc = 0; kc < 8; ++kc) {
    s8v v = WhpV[((32 + wid) * 8 + kc) * 64 + lane];
    *(s8v*)&WhN[(wid * 8 + kc) * 512 + lane * 8] = v;
  }

  const int u0 = 16 * wid + 4 * fq;        // own unit quad
  const int sw = (bb & 7) << 2;            // ystage bank swizzle (4-float gran)

  const f4r bhn4 = *(const f4r*)&bhh[2 * H_ + u0];

  // init ystage with current h state
  {
    f4r h0 = {0.f, 0.f, 0.f, 0.f};
    if (t0c != 0) h0 = *(const f4r*)&hbuf[(size_t)(b0 + bb) * H_ + u0];
    *(f4r*)&ystage[bb * 256 + (u0 ^ sw)] = h0;
  }

  // builder role: wave pair (2k,2k+1) builds k-chunk k, halves sh=0/1
  const int kc_b = wid >> 1;
  const int sh   = wid & 1;
  const int ub   = 32 * kc_b + 8 * fq + 4 * sh;   // u-quad this thread packs

  f4r hn4 = {0.f, 0.f, 0.f, 0.f};

  for (int t = 0; t < CH; ++t) {
    __syncthreads();   // bar0: ystage holds h state for this step

    // P1a: own h quad; flush y row (t0c+t-1)
    f4r hp4 = *(const f4r*)&ystage[bb * 256 + (u0 ^ sw)];
    if (!last && t > 0) {
      __builtin_nontemporal_store(hp4,
          (f4r*)&y[((size_t)(b0 + bb) * S_ + (t0c + t - 1)) * H_ + u0]);
    }

    // P1b: build half k-chunk of shared A-frags from ystage
    {
      f4r hv = *(const f4r*)&ystage[bb * 256 + (ub ^ sw)];
      s4v hh, hl;
      #pragma unroll
      for (int j = 0; j < 4; ++j) {
        unsigned short hi = f2bf(hv[j]);
        hh[j] = (short)hi;
        hl[j] = (short)f2bf(hv[j] - bf2f(hi));
      }
      *(s4v*)&Ahh[kc_b * 512 + lane * 8 + 4 * sh] = hh;
      *(s4v*)&Ahl[kc_b * 512 + lane * 8 + 4 * sh] = hl;
    }

    // stream group kc=0: z-hi, r-lo, z-lo, n-lo (issued before the barrier)
    s8v wlb[2][4];
    wlb[0][0] = WhpV[((16 + wid) * 8 + 0) * 64 + lane];
    wlb[0][1] = WlpV[((     wid) * 8 + 0) * 64 + lane];
    wlb[0][2] = WlpV[((16 + wid) * 8 + 0) * 64 + lane];
    wlb[0][3] = WlpV[((32 + wid) * 8 + 0) * 64 + lane];

    __syncthreads();   // bar1: A-frags visible

    f4v accR = {}, accZ = {}, accN = {};
    f4r xr4, xz4, xn4;
    #pragma unroll
    for (int kc = 0; kc < 8; ++kc) {
      if (kc < 7) {
        wlb[(kc + 1) & 1][0] = WhpV[((16 + wid) * 8 + kc + 1) * 64 + lane];
        wlb[(kc + 1) & 1][1] = WlpV[((     wid) * 8 + kc + 1) * 64 + lane];
        wlb[(kc + 1) & 1][2] = WlpV[((16 + wid) * 8 + kc + 1) * 64 + lane];
        wlb[(kc + 1) & 1][3] = WlpV[((32 + wid) * 8 + kc + 1) * 64 + lane];
      }
      if (kc == 6) {   // gx loads late: short register lifetime, HBM latency
        const float* gb = gx + ((size_t)(b0 + bb) * CH + t) * G3_;
        xr4 = __builtin_nontemporal_load((const f4r*)(gb + u0));
        xz4 = __builtin_nontemporal_load((const f4r*)(gb + H_ + u0));
        xn4 = __builtin_nontemporal_load((const f4r*)(gb + 2 * H_ + u0));
      }
      s8v ahh = *(const s8v*)&Ahh[kc * 512 + lane * 8];
      s8v ahl = *(const s8v*)&Ahl[kc * 512 + lane * 8];
      s8v wn  = *(const s8v*)&WhN[(wid * 8 + kc) * 512 + lane * 8];
      const s8v zh = wlb[kc & 1][0];
      const s8v lr = wlb[kc & 1][1];
      const s8v lz = wlb[kc & 1][2];
      const s8v ln = wlb[kc & 1][3];
      accR = MF(whr[kc], ahh, accR);
      accN = MF(wn,      ahh, accN);
      accZ = MF(zh,      ahh, accZ);
      accR = MF(whr[kc], ahl, accR);
      accN = MF(wn,      ahl, accN);
      accZ = MF(zh,      ahl, accZ);
      accR = MF(lr,      ahh, accR);
      accN = MF(ln,      ahh, accN);
      accZ = MF(lz,      ahh, accZ);
    }

    // epilogue: gate math, write h_new back to ystage
    #pragma unroll
    for (int i = 0; i < 4; ++i) {
      const float r = sigm(xr4[i] + accR[i]);
      const float z = sigm(xz4[i] + accZ[i]);
      const float n = tanh_f(xn4[i] + r * (accN[i] + bhn4[i]));
      hn4[i] = (1.f - z) * n + z * hp4[i];
    }
    *(f4r*)&ystage[bb * 256 + (u0 ^ sw)] = hn4;
  }

  // tail: flush final y row + persist h
  __syncthreads();
  if (!last) {
    f4r v = *(const f4r*)&ystage[bb * 256 + (u0 ^ sw)];
    __builtin_nontemporal_store(v,
        (f4r*)&y[((size_t)(b0 + bb) * S_ + (t0c + CH - 1)) * H_ + u0]);
  }
  *(f4r*)&hbuf[(size_t)(b0 + bb) * H_ + u0] = hn4;
}

// ---------------------------------------------------------------------------
// Head: LayerNorm(h_last) -> MLP 256->32 (ReLU) -> 32->1. One wave per batch.
// ---------------------------------------------------------------------------
__global__ __launch_bounds__(64) void head_kernel(
    const float* __restrict__ hlast, const float* __restrict__ lng,
    const float* __restrict__ lnb, const float* __restrict__ W1,
    const float* __restrict__ b1, const float* __restrict__ W2,
    const float* __restrict__ b2, float* __restrict__ out)
{
  const int b = blockIdx.x;
  const int lane = threadIdx.x;
  float4 v = *(const float4*)&hlast[(size_t)b * H_ + lane * 4];
  float s = v.x + v.y + v.z + v.w;
  #pragma unroll
  for (int m = 32; m > 0; m >>= 1) s += __shfl_xor(s, m, 64);
  const float mu = s * (1.f / 256.f);
  const float dx = v.x - mu, dy = v.y - mu, dz = v.z - mu, dw = v.w - mu;
  float q = dx*dx + dy*dy + dz*dz + dw*dw;
  #pragma unroll
  for (int m = 32; m > 0; m >>= 1) q += __shfl_xor(q, m, 64);
  const float rstd = rsqrtf(q * (1.f / 256.f) + 1e-5f);

  __shared__ float ln[256];
  const int i4 = lane * 4;
  ln[i4 + 0] = dx * rstd * lng[i4 + 0] + lnb[i4 + 0];
  ln[i4 + 1] = dy * rstd * lng[i4 + 1] + lnb[i4 + 1];
  ln[i4 + 2] = dz * rstd * lng[i4 + 2] + lnb[i4 + 2];
  ln[i4 + 3] = dw * rstd * lng[i4 + 3] + lnb[i4 + 3];
  __syncthreads();

  float hd = 0.f;
  if (lane < 32) {
    const float* w = W1 + (size_t)lane * H_;
    float a = 0.f;
    for (int k = 0; k < H_; ++k) a += ln[k] * w[k];
    a += b1[lane];
    hd = fmaxf(a, 0.f) * W2[lane];
  }
  #pragma unroll
  for (int m = 16; m > 0; m >>= 1) hd += __shfl_xor(hd, m, 64);
  if (lane == 0) out[b] = hd + b2[0];
}

// ---------------------------------------------------------------------------
extern "C" void kernel_launch(void* const* d_in, const int* in_sizes, int n_in,
                              void* d_out, int out_size, void* d_ws, size_t ws_size,
                              hipStream_t stream)
{
  const float* x     = (const float*)d_in[0];
  const float* W_ih0 = (const float*)d_in[1];
  const float* W_ihr = (const float*)d_in[2];
  const float* W_hh  = (const float*)d_in[3];
  const float* b_ih  = (const float*)d_in[4];
  const float* b_hh  = (const float*)d_in[5];
  const float* lng   = (const float*)d_in[6];
  const float* lnb   = (const float*)d_in[7];
  const float* W1    = (const float*)d_in[8];
  const float* b1    = (const float*)d_in[9];
  const float* W2    = (const float*)d_in[10];
  const float* b2    = (const float*)d_in[11];
  float* out = (float*)d_out;

  const size_t y_elems   = (size_t)B_ * S_ * H_;       // 134 MB
  const size_t h_elems   = (size_t)B_ * H_;
  const size_t wpk_bytes = (size_t)G3_ * H_ * 2;       // 384 KB each (bf16)

  int CH = 512;
  while (CH > 64) {
    size_t need = (y_elems + (size_t)B_ * CH * G3_ + h_elems + 768) * 4
                + 2 * wpk_bytes + 4096;
    if (need <= ws_size) break;
    CH >>= 1;
  }
  const int chsh = __builtin_ctz((unsigned)CH);

  float* y    = (float*)d_ws;
  float* gx   = y + y_elems;
  float* hbuf = gx + (size_t)B_ * CH * G3_;
  unsigned short* Whp = (unsigned short*)(hbuf + h_elems);
  unsigned short* Wlp = Whp + (size_t)G3_ * H_;
  float* bias2 = (float*)(Wlp + (size_t)G3_ * H_);

  const size_t lds_bytes = 131072 + 8192 + 8192 + 16384;   // 160 KiB

  for (int l = 0; l < 3; ++l) {
    const float* Wih   = (l == 0) ? W_ih0 : (W_ihr + (size_t)(l - 1) * G3_ * H_);
    const int    K     = (l == 0) ? D_ : H_;
    const float* A     = (l == 0) ? x : y;
    const float* Whh_l = W_hh + (size_t)l * G3_ * H_;
    const float* bih_l = b_ih + (size_t)l * G3_;
    const float* bhh_l = b_hh + (size_t)l * G3_;
    const int last = (l == 2) ? 1 : 0;

    bias2_k<<<1, 768, 0, stream>>>(bih_l, bhh_l, bias2);
    pack_whh<<<dim3(48, 8), 64, 0, stream>>>(Whh_l, Whp, Wlp);

    for (int t0 = 0; t0 < S_; t0 += CH) {
      gemm_mfma<<<dim3(G3_ / 64, (B_ * CH) / 64), 256, 0, stream>>>(
          A, Wih, bias2, gx, K, chsh, t0);
      gru_scan<<<16, 1024, lds_bytes, stream>>>(
          gx, Whp, Wlp, bhh_l, hbuf, y, CH, t0, last);
    }
  }

  head_kernel<<<256, 64, 0, stream>>>(hbuf, lng, lnb, W1, b1, W2, b2, out);
}

// Round 9
// 8023.637 us; speedup vs baseline: 2.5837x; 2.5837x over previous
//
#include <hip/hip_runtime.h>
#include <stdint.h>

#define B_  256
#define S_  512
#define D_  64
#define H_  256
#define G3_ 768

typedef __attribute__((ext_vector_type(8))) short s8v;   // 8 bf16 (4 VGPRs)
typedef __attribute__((ext_vector_type(4))) short s4v;   // 4 bf16 (2 VGPRs)
typedef __attribute__((ext_vector_type(4))) float f4v;   // MFMA accumulator
typedef __attribute__((ext_vector_type(4))) float f4r;   // raw float4 (NT-capable)

#define MF(a, b, c) __builtin_amdgcn_mfma_f32_16x16x32_bf16((a), (b), (c), 0, 0, 0)

__device__ __forceinline__ unsigned short f2bf(float x) {  // RNE
  unsigned u = __float_as_uint(x);
  unsigned r = (u + 0x7fffu + ((u >> 16) & 1u)) >> 16;
  return (unsigned short)r;
}
__device__ __forceinline__ float bf2f(unsigned short s) {
  return __uint_as_float(((unsigned)s) << 16);
}
__device__ __forceinline__ float sigm(float x) {
  return __builtin_amdgcn_rcpf(1.f + __expf(-x));
}
__device__ __forceinline__ float tanh_f(float x) {
  return 1.f - 2.f * __builtin_amdgcn_rcpf(1.f + __expf(2.f * x));
}

// ---------------------------------------------------------------------------
// MFMA bf16-split input GEMM (3-pass, fp32-class accuracy; unchanged).
// ---------------------------------------------------------------------------
__global__ __launch_bounds__(256) void gemm_mfma(
    const float* __restrict__ A, const float* __restrict__ W,
    const float* __restrict__ bias, float* __restrict__ C,
    int K, int chsh, int t0)
{
  const int g0 = blockIdx.x * 64;
  const int r0 = blockIdx.y * 64;
  const int tid = threadIdx.x;
  const int w = tid >> 6, l = tid & 63;
  const int fr = l & 15, fq = l >> 4;

  __shared__ unsigned short Ah[64][40], Al[64][40];
  __shared__ unsigned short Wh[64][40], Wl[64][40];

  f4v acc[4] = {};

  const int row = tid >> 2, q = tid & 3;
  const int CHm1 = (1 << chsh) - 1;
  const int r = r0 + row;
  const int rg = ((r >> chsh) * S_) + t0 + (r & CHm1);
  const float* ap = A + (size_t)rg * K + q * 8;
  const float* wp = W + (size_t)(g0 + row) * K + q * 8;

  for (int k0 = 0; k0 < K; k0 += 32) {
    float4 a0 = *(const float4*)(ap + k0);
    float4 a1 = *(const float4*)(ap + k0 + 4);
    float4 w0 = *(const float4*)(wp + k0);
    float4 w1 = *(const float4*)(wp + k0 + 4);
    __syncthreads();
    float av[8] = {a0.x,a0.y,a0.z,a0.w,a1.x,a1.y,a1.z,a1.w};
    float wv[8] = {w0.x,w0.y,w0.z,w0.w,w1.x,w1.y,w1.z,w1.w};
    unsigned short ah[8], al_[8], wh[8], wl_[8];
    #pragma unroll
    for (int i = 0; i < 8; ++i) {
      ah[i]  = f2bf(av[i]);  al_[i] = f2bf(av[i] - bf2f(ah[i]));
      wh[i]  = f2bf(wv[i]);  wl_[i] = f2bf(wv[i] - bf2f(wh[i]));
    }
    *(s8v*)&Ah[row][q*8] = *(s8v*)ah;  *(s8v*)&Al[row][q*8] = *(s8v*)al_;
    *(s8v*)&Wh[row][q*8] = *(s8v*)wh;  *(s8v*)&Wl[row][q*8] = *(s8v*)wl_;
    __syncthreads();

    s8v a_hi = *(const s8v*)&Ah[w*16 + fr][fq*8];
    s8v a_lo = *(const s8v*)&Al[w*16 + fr][fq*8];
    #pragma unroll
    for (int c = 0; c < 4; ++c) {
      s8v b_hi = *(const s8v*)&Wh[c*16 + fr][fq*8];
      s8v b_lo = *(const s8v*)&Wl[c*16 + fr][fq*8];
      acc[c] = MF(a_hi, b_hi, acc[c]);
      acc[c] = MF(a_lo, b_hi, acc[c]);
      acc[c] = MF(a_hi, b_lo, acc[c]);
    }
  }

  const int orow = r0 + w * 16 + fq * 4;
  #pragma unroll
  for (int c = 0; c < 4; ++c) {
    const float bi = bias[g0 + c * 16 + fr];
    #pragma unroll
    for (int i = 0; i < 4; ++i) {
      float v = acc[c][i] + bi;
      __builtin_nontemporal_store(v, &C[(size_t)(orow + i) * G3_ + g0 + c * 16 + fr]);
    }
  }
}

// ---------------------------------------------------------------------------
// Pack W_hh into MFMA fragment order, bf16-hi only (scan is hi-resident now).
// ---------------------------------------------------------------------------
__global__ __launch_bounds__(64) void pack_whh(
    const float* __restrict__ Whh, unsigned short* __restrict__ Whp)
{
  const int gti = blockIdx.x, kc = blockIdx.y, lane = threadIdx.x;
  const int row = gti * 16 + (lane & 15);
  const int k0  = kc * 32 + (lane >> 4) * 8;
  const float* src = &Whh[(size_t)row * H_ + k0];
  unsigned short hi8[8];
  #pragma unroll
  for (int s = 0; s < 8; ++s) hi8[s] = f2bf(src[s]);
  const size_t o = ((size_t)(gti * 8 + kc) * 64 + lane) * 8;
  *(s8v*)&Whp[o] = *(s8v*)hi8;
}

__global__ __launch_bounds__(768) void bias2_k(
    const float* __restrict__ bih, const float* __restrict__ bhh,
    float* __restrict__ bias2)
{
  int g = threadIdx.x;
  bias2[g] = bih[g] + (g < 512 ? bhh[g] : 0.f);
}

// ---------------------------------------------------------------------------
// MFMA GRU scan v4 — ZERO weight stream. 16 WGs x 1024 thr (16 waves).
// Wave w owns units [16w,16w+16): r-hi (32 VGPR) + z-hi (32 VGPR) resident,
// n-hi resident in LDS (128KB). W quantized to single bf16 (hi); h still
// split hi/lo (2 A-passes). Per kc: 6 MFMA, 3 LDS b128 reads. 2 barriers.
// h state in ystage LDS (doubles as y-flush stage). Zero cross-WG sync.
// ---------------------------------------------------------------------------
__global__ __launch_bounds__(1024, 4) void gru_scan(
    const float* __restrict__ gx, const unsigned short* __restrict__ Whp,
    const float* __restrict__ bhh, float* __restrict__ hbuf,
    float* __restrict__ y, int CH, int t0c, int last)
{
  const int bid = blockIdx.x;          // 16
  const int b0  = bid * 16;
  const int tid = threadIdx.x;
  const int wid = tid >> 6, lane = tid & 63;
  const int bb = lane & 15;            // batch-local (D col)
  const int fq = lane >> 4;            // row quad (D rows 4fq..4fq+3)

  extern __shared__ unsigned short lds_[];
  unsigned short* WhN = lds_;                       // [16 w][8 kc][512] = 128KB
  unsigned short* Ahh = lds_ + 65536;               // [8 kc][512] = 8KB
  unsigned short* Ahl = Ahh + 4096;                 // 8KB
  float* ystage = (float*)(Ahl + 4096);             // [16 bb][256 u] = 16KB, swz

  const s8v* WhpV = (const s8v*)Whp;

  // resident r-hi and z-hi tiles (64 VGPR)
  s8v whr[8], whz[8];
  #pragma unroll
  for (int kc = 0; kc < 8; ++kc) {
    whr[kc] = WhpV[((     wid) * 8 + kc) * 64 + lane];
    whz[kc] = WhpV[((16 + wid) * 8 + kc) * 64 + lane];
  }
  // n-hi tile -> LDS (each wave its own 8KB region)
  #pragma unroll
  for (int kc = 0; kc < 8; ++kc) {
    s8v v = WhpV[((32 + wid) * 8 + kc) * 64 + lane];
    *(s8v*)&WhN[(wid * 8 + kc) * 512 + lane * 8] = v;
  }

  const int u0 = 16 * wid + 4 * fq;        // own unit quad
  const int sw = (bb & 7) << 2;            // ystage bank swizzle (4-float gran)

  const f4r bhn4 = *(const f4r*)&bhh[2 * H_ + u0];

  // init ystage with current h state
  {
    f4r h0 = {0.f, 0.f, 0.f, 0.f};
    if (t0c != 0) h0 = *(const f4r*)&hbuf[(size_t)(b0 + bb) * H_ + u0];
    *(f4r*)&ystage[bb * 256 + (u0 ^ sw)] = h0;
  }

  // builder role: wave pair (2k,2k+1) builds k-chunk k, halves sh=0/1
  const int kc_b = wid >> 1;
  const int sh   = wid & 1;
  const int ub   = 32 * kc_b + 8 * fq + 4 * sh;   // u-quad this thread packs

  f4r hn4 = {0.f, 0.f, 0.f, 0.f};

  for (int t = 0; t < CH; ++t) {
    __syncthreads();   // bar0: ystage holds h state for this step

    // own h quad; flush y row (t0c+t-1); gx issued early (HBM latency hides
    // under A-build + bar1 + MFMA loop)
    f4r hp4 = *(const f4r*)&ystage[bb * 256 + (u0 ^ sw)];
    if (!last && t > 0) {
      __builtin_nontemporal_store(hp4,
          (f4r*)&y[((size_t)(b0 + bb) * S_ + (t0c + t - 1)) * H_ + u0]);
    }
    const float* gb = gx + ((size_t)(b0 + bb) * CH + t) * G3_;
    f4r xr4 = __builtin_nontemporal_load((const f4r*)(gb + u0));
    f4r xz4 = __builtin_nontemporal_load((const f4r*)(gb + H_ + u0));
    f4r xn4 = __builtin_nontemporal_load((const f4r*)(gb + 2 * H_ + u0));

    // build half k-chunk of shared A-frags from ystage
    {
      f4r hv = *(const f4r*)&ystage[bb * 256 + (ub ^ sw)];
      s4v hh, hl;
      #pragma unroll
      for (int j = 0; j < 4; ++j) {
        unsigned short hi = f2bf(hv[j]);
        hh[j] = (short)hi;
        hl[j] = (short)f2bf(hv[j] - bf2f(hi));
      }
      *(s4v*)&Ahh[kc_b * 512 + lane * 8 + 4 * sh] = hh;
      *(s4v*)&Ahl[kc_b * 512 + lane * 8 + 4 * sh] = hl;
    }

    __syncthreads();   // bar1: A-frags visible

    f4v accR = {}, accZ = {}, accN = {};
    #pragma unroll
    for (int kc = 0; kc < 8; ++kc) {
      s8v ahh = *(const s8v*)&Ahh[kc * 512 + lane * 8];
      s8v ahl = *(const s8v*)&Ahl[kc * 512 + lane * 8];
      s8v wn  = *(const s8v*)&WhN[(wid * 8 + kc) * 512 + lane * 8];
      accR = MF(whr[kc], ahh, accR);
      accZ = MF(whz[kc], ahh, accZ);
      accN = MF(wn,      ahh, accN);
      accR = MF(whr[kc], ahl, accR);
      accZ = MF(whz[kc], ahl, accZ);
      accN = MF(wn,      ahl, accN);
    }

    // epilogue: gate math, write h_new back to ystage
    #pragma unroll
    for (int i = 0; i < 4; ++i) {
      const float r = sigm(xr4[i] + accR[i]);
      const float z = sigm(xz4[i] + accZ[i]);
      const float n = tanh_f(xn4[i] + r * (accN[i] + bhn4[i]));
      hn4[i] = (1.f - z) * n + z * hp4[i];
    }
    *(f4r*)&ystage[bb * 256 + (u0 ^ sw)] = hn4;
  }

  // tail: flush final y row + persist h
  __syncthreads();
  if (!last) {
    f4r v = *(const f4r*)&ystage[bb * 256 + (u0 ^ sw)];
    __builtin_nontemporal_store(v,
        (f4r*)&y[((size_t)(b0 + bb) * S_ + (t0c + CH - 1)) * H_ + u0]);
  }
  *(f4r*)&hbuf[(size_t)(b0 + bb) * H_ + u0] = hn4;
}

// ---------------------------------------------------------------------------
// Head: LayerNorm(h_last) -> MLP 256->32 (ReLU) -> 32->1. One wave per batch.
// ---------------------------------------------------------------------------
__global__ __launch_bounds__(64) void head_kernel(
    const float* __restrict__ hlast, const float* __restrict__ lng,
    const float* __restrict__ lnb, const float* __restrict__ W1,
    const float* __restrict__ b1, const float* __restrict__ W2,
    const float* __restrict__ b2, float* __restrict__ out)
{
  const int b = blockIdx.x;
  const int lane = threadIdx.x;
  float4 v = *(const float4*)&hlast[(size_t)b * H_ + lane * 4];
  float s = v.x + v.y + v.z + v.w;
  #pragma unroll
  for (int m = 32; m > 0; m >>= 1) s += __shfl_xor(s, m, 64);
  const float mu = s * (1.f / 256.f);
  const float dx = v.x - mu, dy = v.y - mu, dz = v.z - mu, dw = v.w - mu;
  float q = dx*dx + dy*dy + dz*dz + dw*dw;
  #pragma unroll
  for (int m = 32; m > 0; m >>= 1) q += __shfl_xor(q, m, 64);
  const float rstd = rsqrtf(q * (1.f / 256.f) + 1e-5f);

  __shared__ float ln[256];
  const int i4 = lane * 4;
  ln[i4 + 0] = dx * rstd * lng[i4 + 0] + lnb[i4 + 0];
  ln[i4 + 1] = dy * rstd * lng[i4 + 1] + lnb[i4 + 1];
  ln[i4 + 2] = dz * rstd * lng[i4 + 2] + lnb[i4 + 2];
  ln[i4 + 3] = dw * rstd * lng[i4 + 3] + lnb[i4 + 3];
  __syncthreads();

  float hd = 0.f;
  if (lane < 32) {
    const float* w = W1 + (size_t)lane * H_;
    float a = 0.f;
    for (int k = 0; k < H_; ++k) a += ln[k] * w[k];
    a += b1[lane];
    hd = fmaxf(a, 0.f) * W2[lane];
  }
  #pragma unroll
  for (int m = 16; m > 0; m >>= 1) hd += __shfl_xor(hd, m, 64);
  if (lane == 0) out[b] = hd + b2[0];
}

// ---------------------------------------------------------------------------
extern "C" void kernel_launch(void* const* d_in, const int* in_sizes, int n_in,
                              void* d_out, int out_size, void* d_ws, size_t ws_size,
                              hipStream_t stream)
{
  const float* x     = (const float*)d_in[0];
  const float* W_ih0 = (const float*)d_in[1];
  const float* W_ihr = (const float*)d_in[2];
  const float* W_hh  = (const float*)d_in[3];
  const float* b_ih  = (const float*)d_in[4];
  const float* b_hh  = (const float*)d_in[5];
  const float* lng   = (const float*)d_in[6];
  const float* lnb   = (const float*)d_in[7];
  const float* W1    = (const float*)d_in[8];
  const float* b1    = (const float*)d_in[9];
  const float* W2    = (const float*)d_in[10];
  const float* b2    = (const float*)d_in[11];
  float* out = (float*)d_out;

  const size_t y_elems   = (size_t)B_ * S_ * H_;       // 134 MB
  const size_t h_elems   = (size_t)B_ * H_;
  const size_t whp_elems = (size_t)G3_ * H_;           // bf16-hi pack

  int CH = 512;
  while (CH > 64) {
    size_t need = (y_elems + (size_t)B_ * CH * G3_ + h_elems + 768) * 4
                + whp_elems * 2 + 4096;
    if (need <= ws_size) break;
    CH >>= 1;
  }
  const int chsh = __builtin_ctz((unsigned)CH);

  float* y    = (float*)d_ws;
  float* gx   = y + y_elems;
  float* hbuf = gx + (size_t)B_ * CH * G3_;
  unsigned short* Whp = (unsigned short*)(hbuf + h_elems);
  float* bias2 = (float*)(Whp + whp_elems);

  const size_t lds_bytes = 131072 + 8192 + 8192 + 16384;   // 160 KiB

  for (int l = 0; l < 3; ++l) {
    const float* Wih   = (l == 0) ? W_ih0 : (W_ihr + (size_t)(l - 1) * G3_ * H_);
    const int    K     = (l == 0) ? D_ : H_;
    const float* A     = (l == 0) ? x : y;
    const float* Whh_l = W_hh + (size_t)l * G3_ * H_;
    const float* bih_l = b_ih + (size_t)l * G3_;
    const float* bhh_l = b_hh + (size_t)l * G3_;
    const int last = (l == 2) ? 1 : 0;

    bias2_k<<<1, 768, 0, stream>>>(bih_l, bhh_l, bias2);
    pack_whh<<<dim3(48, 8), 64, 0, stream>>>(Whh_l, Whp);

    for (int t0 = 0; t0 < S_; t0 += CH) {
      gemm_mfma<<<dim3(G3_ / 64, (B_ * CH) / 64), 256, 0, stream>>>(
          A, Wih, bias2, gx, K, chsh, t0);
      gru_scan<<<16, 1024, lds_bytes, stream>>>(
          gx, Whp, bhh_l, hbuf, y, CH, t0, last);
    }
  }

  head_kernel<<<256, 64, 0, stream>>>(hbuf, lng, lnb, W1, b1, W2, b2, out);
}